// Round 9
// baseline (273.348 us; speedup 1.0000x reference)
//
#include <hip/hip_runtime.h>
#include <math.h>

// Problem constants (match reference)
constexpr int D_ = 64;
constexpr int N_ = 8192;
constexpr int DIM_ = 256;
constexpr int K_ = 32;
constexpr int L_ = 1;
constexpr int P_ = D_ - L_;  // 63
constexpr float TEMP_ = 0.1f;
constexpr float EPS_ = 1e-8f;

constexpr int CHUNKS = 32;   // blocks per d
constexpr int CROWS = 256;   // rows per block
constexpr int BROWS = 8;     // rows per register batch
constexpr int LDSTR = 65;    // scratch stride (words) -> 2-way (free) banks

// Kernel 1: r4 streaming structure + register-staged double-buffered loads.
// Per (d,chunk) block: 4 waves x 64 consecutive rows, 8 batches of 8 rows.
// Batch t+1's loads are issued into the alternate register buffer BEFORE
// computing batch t, so HBM latency hides under the square/reduce work
// (breaks the convoy that capped r4 at ~4.4 TB/s).
__global__ __launch_bounds__(256, 4) void k1_sums_norms(const float* __restrict__ emb,
                                                        float* __restrict__ normsq,
                                                        float* __restrict__ sum_all) {
  const int b = blockIdx.x;
  const int d = b >> 5;
  const int chunk = b & 31;
  const int tid = threadIdx.x;
  const int wave = tid >> 6;
  const int lane = tid & 63;
  const float* base = emb + (size_t)d * N_ * DIM_;

  __shared__ __align__(16) float sq[4][BROWS * LDSTR];  // 8.1 KB (also colsum stash)

  float a0 = 0.f, a1 = 0.f, a2 = 0.f, a3 = 0.f;
  const int wrow0 = chunk * CROWS + wave * 64;
  const float* wbase = base + (size_t)wrow0 * DIM_ + (lane << 2);

  float4 bufA[BROWS], bufB[BROWS];

#define LOADB(buf, t)                                                        \
  _Pragma("unroll") for (int r = 0; r < BROWS; ++r)                          \
      buf[r] = *reinterpret_cast<const float4*>(wbase + ((size_t)(t) * BROWS + r) * DIM_);

#define COMPUTEB(buf, t)                                                     \
  {                                                                          \
    _Pragma("unroll") for (int r = 0; r < BROWS; ++r) {                      \
      a0 += buf[r].x; a1 += buf[r].y; a2 += buf[r].z; a3 += buf[r].w;        \
      sq[wave][r * LDSTR + lane] =                                           \
          buf[r].x * buf[r].x + buf[r].y * buf[r].y +                        \
          buf[r].z * buf[r].z + buf[r].w * buf[r].w;                         \
    }                                                                        \
    const int rr = lane >> 3, s = lane & 7;                                  \
    const float* p = &sq[wave][rr * LDSTR + s * 8];                          \
    float sum = p[0] + p[1] + p[2] + p[3] + p[4] + p[5] + p[6] + p[7];       \
    sum += __shfl_xor(sum, 1, 64);                                           \
    sum += __shfl_xor(sum, 2, 64);                                           \
    sum += __shfl_xor(sum, 4, 64);                                           \
    if (s == 0) normsq[(size_t)d * N_ + wrow0 + (t) * BROWS + rr] = sum;     \
  }

  LOADB(bufA, 0)
  for (int tt = 0; tt < 4; ++tt) {
    const int t0 = 2 * tt;
    if (t0 + 1 < 8) LOADB(bufB, t0 + 1)
    COMPUTEB(bufA, t0)
    if (t0 + 2 < 8) LOADB(bufA, t0 + 2)
    COMPUTEB(bufB, t0 + 1)
  }
#undef LOADB
#undef COMPUTEB

  // Colsum epilogue (as r4): own-wave stash, barrier, cross-wave combine.
  reinterpret_cast<float4*>(&sq[wave][0])[lane] = make_float4(a0, a1, a2, a3);
  __syncthreads();
  const float s = sq[0][tid] + sq[1][tid] + sq[2][tid] + sq[3][tid];
  atomicAdd(&sum_all[d * DIM_ + tid], s);
}

// Kernel 2+3 fused (exact r4 version): one block per d. Top-K by norm^2
// (stable lowest-index tie-break, matching jnp.argsort(-norms)), then
// gather + samples + normalize.
__global__ __launch_bounds__(256) void k23_topk_samples(const float* __restrict__ emb,
                                                        const float* __restrict__ normsq,
                                                        const float* __restrict__ sum_all,
                                                        float* __restrict__ nS,
                                                        float* __restrict__ out) {
  const int d = blockIdx.x;
  const int tid = threadIdx.x;
  const int lane = tid & 63;
  const int wave = tid >> 6;

  __shared__ float vals[N_];  // 32 KB
  __shared__ unsigned long long wbest[4];
  __shared__ int topidx[K_];

  for (int i = tid; i < N_; i += 256) vals[i] = normsq[(size_t)d * N_ + i];
  __syncthreads();

  // key = (float bits)<<32 | (N-1-i): larger norm wins, then lower index
  // (valid: norms^2 >= 0 so the float bit pattern is order-preserving).
  unsigned long long my = 0ull;
#pragma unroll 8
  for (int r = 0; r < 32; ++r) {
    const int i = tid + (r << 8);
    const unsigned long long key =
        ((unsigned long long)__float_as_uint(vals[i]) << 32) | (unsigned)(N_ - 1 - i);
    if (key > my) my = key;
  }

  for (int k = 0; k < K_; ++k) {
    unsigned long long bw = my;
#pragma unroll
    for (int off = 1; off < 64; off <<= 1) {
      const unsigned long long o = __shfl_xor(bw, off, 64);
      if (o > bw) bw = o;
    }
    if (lane == 0) wbest[wave] = bw;
    __syncthreads();
    unsigned long long bb = wbest[0];
    for (int w = 1; w < 4; ++w)
      if (wbest[w] > bb) bb = wbest[w];
    const int idx = N_ - 1 - (int)(bb & 0xFFFFFFFFu);
    if (tid == 0) topidx[k] = idx;
    if ((idx & 255) == tid) {  // owner removes + rescans its strided chunk
      vals[idx] = 0.0f;
      my = 0ull;
      for (int r = 0; r < 32; ++r) {
        const int i = tid + (r << 8);
        const unsigned long long key =
            ((unsigned long long)__float_as_uint(vals[i]) << 32) | (unsigned)(N_ - 1 - i);
        if (key > my) my = key;
      }
    }
    __syncthreads();
  }

  // ---- samples + normalize ----
  const float* base = emb + (size_t)d * N_ * DIM_;
  float ts = 0.f;
#pragma unroll 4
  for (int k = 0; k < K_; ++k) {
    ts += base[(size_t)topidx[k] * DIM_ + tid];
  }
  const float s1 = sum_all[d * DIM_ + tid];
  const float s2 = s1 - ts;

  float q1 = s1 * s1, q2 = s2 * s2;
#pragma unroll
  for (int off = 32; off > 0; off >>= 1) {
    q1 += __shfl_down(q1, off, 64);
    q2 += __shfl_down(q2, off, 64);
  }
  __shared__ float w1[4], w2[4];
  __shared__ float inv1s, inv2s;
  if (lane == 0) { w1[wave] = q1; w2[wave] = q2; }
  __syncthreads();
  if (tid == 0) {
    const float n1 = sqrtf(w1[0] + w1[1] + w1[2] + w1[3]);
    const float n2 = sqrtf(w2[0] + w2[1] + w2[2] + w2[3]);
    inv1s = 1.0f / fmaxf(n1, EPS_);
    inv2s = 1.0f / fmaxf(n2, EPS_);
    if (d == 0) out[0] = 0.0f;  // zero loss accumulator (ordered before k4)
  }
  __syncthreads();
  nS[d * DIM_ + tid] = s1 * inv1s;
  nS[(D_ + d) * DIM_ + tid] = s2 * inv2s;
}

// Loss kernel: 4 waves per pair; wave w handles 8 negatives for both sides
// with an online (max, sumexp) held uniformly in all lanes, combined via LDS.
__global__ __launch_bounds__(256) void k4_loss(const float* __restrict__ nS,
                                               const int* __restrict__ negidx,
                                               float* __restrict__ out) {
  const int p = blockIdx.x;
  const int tid = threadIdx.x;
  const int wave = tid >> 6;
  const int lane = tid & 63;

  const float4 vi = *reinterpret_cast<const float4*>(nS + p * DIM_ + (lane << 2));
  const float4 vj = *reinterpret_cast<const float4*>(nS + (p + L_) * DIM_ + (lane << 2));

  float dp = vi.x * vj.x + vi.y * vj.y + vi.z * vj.z + vi.w * vj.w;
#pragma unroll
  for (int off = 1; off < 64; off <<= 1) dp += __shfl_xor(dp, off, 64);
  const float invT = 1.0f / TEMP_;
  const float posT = dp * invT;

  float mi = -INFINITY, si = 0.f, mj = -INFINITY, sj = 0.f;
#pragma unroll
  for (int kk = 0; kk < K_ / 4; ++kk) {
    const int k = wave * (K_ / 4) + kk;
    const int idx = negidx[p * K_ + k];
    const float4 vn = *reinterpret_cast<const float4*>(nS + idx * DIM_ + (lane << 2));
    float di = vi.x * vn.x + vi.y * vn.y + vi.z * vn.z + vi.w * vn.w;
    float dj = vj.x * vn.x + vj.y * vn.y + vj.z * vn.z + vj.w * vn.w;
#pragma unroll
    for (int off = 1; off < 64; off <<= 1) {
      di += __shfl_xor(di, off, 64);
      dj += __shfl_xor(dj, off, 64);
    }
    const float li = di * invT;
    const float lj = dj * invT;
    if (li > mi) { si = si * expf(mi - li) + 1.f; mi = li; } else { si += expf(li - mi); }
    if (lj > mj) { sj = sj * expf(mj - lj) + 1.f; mj = lj; } else { sj += expf(lj - mj); }
  }

  __shared__ float pm[2][4], ps[2][4];
  if (lane == 0) {
    pm[0][wave] = mi; ps[0][wave] = si;
    pm[1][wave] = mj; ps[1][wave] = sj;
  }
  __syncthreads();
  if (tid == 0) {
    float total = 0.f;
#pragma unroll
    for (int side = 0; side < 2; ++side) {
      float m = posT;
      for (int w = 0; w < 4; ++w) m = fmaxf(m, pm[side][w]);
      float s = expf(posT - m);
      for (int w = 0; w < 4; ++w) s += ps[side][w] * expf(pm[side][w] - m);
      total += m + logf(s) - posT;  // lse - posT
    }
    atomicAdd(out, total / (2.0f * P_));
  }
}

extern "C" void kernel_launch(void* const* d_in, const int* in_sizes, int n_in,
                              void* d_out, int out_size, void* d_ws, size_t ws_size,
                              hipStream_t stream) {
  const float* emb = (const float*)d_in[0];
  const int* negidx = (const int*)d_in[1];
  float* out = (float*)d_out;

  // Workspace layout (floats):
  float* normsq = (float*)d_ws;                 // D*N = 524288
  float* sum_all = normsq + (size_t)D_ * N_;    // D*DIM = 16384
  float* nS = sum_all + D_ * DIM_;              // 2*D*DIM = 32768

  hipMemsetAsync(sum_all, 0, D_ * DIM_ * sizeof(float), stream);

  k1_sums_norms<<<D_ * CHUNKS, 256, 0, stream>>>(emb, normsq, sum_all);
  k23_topk_samples<<<D_, 256, 0, stream>>>(emb, normsq, sum_all, nS, out);
  k4_loss<<<P_, 256, 0, stream>>>(nS, negidx, out);
}

// Round 10
// 149.184 us; speedup vs baseline: 1.8323x; 1.8323x over previous
//
#include <hip/hip_runtime.h>
#include <math.h>

// Problem constants (match reference)
constexpr int D_ = 64;
constexpr int N_ = 8192;
constexpr int DIM_ = 256;
constexpr int K_ = 32;
constexpr int L_ = 1;
constexpr int P_ = D_ - L_;  // 63
constexpr float TEMP_ = 0.1f;
constexpr float EPS_ = 1e-8f;

constexpr int CHUNKS = 32;   // blocks per d
constexpr int CROWS = 256;   // rows per block
constexpr int BATCH = 16;    // rows per wave per LDS round
constexpr int LDSTR = 65;    // scratch stride (words) -> 2-way (free) banks

// Kernel 1: r4's exact streaming structure (150.7us champion). Only delta:
// per-dim sums go to per-chunk partial buffers (plain stores) instead of
// atomicAdd into sum_all — removes the memset dispatch + atomic traffic.
// NOTE (r2..r9 evidence): this loop runs ~4.3-4.4 TB/s read-only, which five
// structurally different variants could not beat; working model is a per-CU
// read-return cap (~7 B/cy/CU). Do not touch the hot loop without new data.
__global__ __launch_bounds__(256, 4) void k1_sums_norms(const float* __restrict__ emb,
                                                        float* __restrict__ normsq,
                                                        float* __restrict__ psum) {
  const int b = blockIdx.x;
  const int d = b >> 5;
  const int chunk = b & 31;
  const int tid = threadIdx.x;
  const int wave = tid >> 6;
  const int lane = tid & 63;
  const float* base = emb + (size_t)d * N_ * DIM_;

  __shared__ __align__(16) float sq[4][BATCH * LDSTR];  // 16.25 KB

  float a0 = 0.f, a1 = 0.f, a2 = 0.f, a3 = 0.f;
  const int wrow0 = chunk * CROWS + wave * 64;

  for (int batch = 0; batch < 64 / BATCH; ++batch) {
    const int r0 = wrow0 + batch * BATCH;
#pragma unroll
    for (int r = 0; r < BATCH; ++r) {
      const float4 v = *reinterpret_cast<const float4*>(base + (size_t)(r0 + r) * DIM_ + (lane << 2));
      a0 += v.x; a1 += v.y; a2 += v.z; a3 += v.w;
      sq[wave][r * LDSTR + lane] = v.x * v.x + v.y * v.y + v.z * v.z + v.w * v.w;
    }
    // Own-wave transpose-reduce: 4 threads/row, 16 adds each, 2 shfl.
    {
      const int rr = tid >> 2;   // in [16*wave, 16*wave+16)
      const int q = tid & 3;
      const int r = rr & 15;
      const float* p = &sq[wave][r * LDSTR + q * 16];
      float s = 0.f;
#pragma unroll
      for (int i = 0; i < 16; ++i) s += p[i];
      s += __shfl_xor(s, 1, 64);
      s += __shfl_xor(s, 2, 64);
      if (q == 0) {
        const int row = chunk * CROWS + wave * 64 + batch * BATCH + r;
        normsq[(size_t)d * N_ + row] = s;
      }
    }
  }

  // Colsum epilogue: own-wave stash, barrier, cross-wave combine, plain store.
  reinterpret_cast<float4*>(&sq[wave][0])[lane] = make_float4(a0, a1, a2, a3);
  __syncthreads();
  const float s = sq[0][tid] + sq[1][tid] + sq[2][tid] + sq[3][tid];
  psum[(size_t)(d * CHUNKS + chunk) * DIM_ + tid] = s;
}

// Kernel 2+3 fused (r4 version + psum reduce): one block per d. Top-K by
// norm^2 (stable lowest-index tie-break, matching jnp.argsort(-norms)),
// then gather + samples + normalize.
__global__ __launch_bounds__(256) void k23_topk_samples(const float* __restrict__ emb,
                                                        const float* __restrict__ normsq,
                                                        const float* __restrict__ psum,
                                                        float* __restrict__ nS,
                                                        float* __restrict__ out) {
  const int d = blockIdx.x;
  const int tid = threadIdx.x;
  const int lane = tid & 63;
  const int wave = tid >> 6;

  __shared__ float vals[N_];  // 32 KB
  __shared__ unsigned long long wbest[4];
  __shared__ int topidx[K_];

  for (int i = tid; i < N_; i += 256) vals[i] = normsq[(size_t)d * N_ + i];

  // Per-dim colsum from the 32 per-chunk partials (independent of top-K).
  float s1 = 0.f;
#pragma unroll 8
  for (int c = 0; c < CHUNKS; ++c)
    s1 += psum[(size_t)(d * CHUNKS + c) * DIM_ + tid];

  __syncthreads();

  // key = (float bits)<<32 | (N-1-i): larger norm wins, then lower index
  // (valid: norms^2 >= 0 so the float bit pattern is order-preserving).
  unsigned long long my = 0ull;
#pragma unroll 8
  for (int r = 0; r < 32; ++r) {
    const int i = tid + (r << 8);
    const unsigned long long key =
        ((unsigned long long)__float_as_uint(vals[i]) << 32) | (unsigned)(N_ - 1 - i);
    if (key > my) my = key;
  }

  for (int k = 0; k < K_; ++k) {
    unsigned long long bw = my;
#pragma unroll
    for (int off = 1; off < 64; off <<= 1) {
      const unsigned long long o = __shfl_xor(bw, off, 64);
      if (o > bw) bw = o;
    }
    if (lane == 0) wbest[wave] = bw;
    __syncthreads();
    unsigned long long bb = wbest[0];
    for (int w = 1; w < 4; ++w)
      if (wbest[w] > bb) bb = wbest[w];
    const int idx = N_ - 1 - (int)(bb & 0xFFFFFFFFu);
    if (tid == 0) topidx[k] = idx;
    if ((idx & 255) == tid) {  // owner removes + rescans its strided chunk
      vals[idx] = 0.0f;
      my = 0ull;
      for (int r = 0; r < 32; ++r) {
        const int i = tid + (r << 8);
        const unsigned long long key =
            ((unsigned long long)__float_as_uint(vals[i]) << 32) | (unsigned)(N_ - 1 - i);
        if (key > my) my = key;
      }
    }
    __syncthreads();
  }

  // ---- samples + normalize ----
  const float* base = emb + (size_t)d * N_ * DIM_;
  float ts = 0.f;
#pragma unroll 4
  for (int k = 0; k < K_; ++k) {
    ts += base[(size_t)topidx[k] * DIM_ + tid];
  }
  const float s2 = s1 - ts;

  float q1 = s1 * s1, q2 = s2 * s2;
#pragma unroll
  for (int off = 32; off > 0; off >>= 1) {
    q1 += __shfl_down(q1, off, 64);
    q2 += __shfl_down(q2, off, 64);
  }
  __shared__ float w1[4], w2[4];
  __shared__ float inv1s, inv2s;
  if (lane == 0) { w1[wave] = q1; w2[wave] = q2; }
  __syncthreads();
  if (tid == 0) {
    const float n1 = sqrtf(w1[0] + w1[1] + w1[2] + w1[3]);
    const float n2 = sqrtf(w2[0] + w2[1] + w2[2] + w2[3]);
    inv1s = 1.0f / fmaxf(n1, EPS_);
    inv2s = 1.0f / fmaxf(n2, EPS_);
    if (d == 0) out[0] = 0.0f;  // zero loss accumulator (ordered before k4)
  }
  __syncthreads();
  nS[d * DIM_ + tid] = s1 * inv1s;
  nS[(D_ + d) * DIM_ + tid] = s2 * inv2s;
}

// Loss kernel: 4 waves per pair; wave w handles 8 negatives for both sides
// with an online (max, sumexp) held uniformly in all lanes, combined via LDS.
__global__ __launch_bounds__(256) void k4_loss(const float* __restrict__ nS,
                                               const int* __restrict__ negidx,
                                               float* __restrict__ out) {
  const int p = blockIdx.x;
  const int tid = threadIdx.x;
  const int wave = tid >> 6;
  const int lane = tid & 63;

  const float4 vi = *reinterpret_cast<const float4*>(nS + p * DIM_ + (lane << 2));
  const float4 vj = *reinterpret_cast<const float4*>(nS + (p + L_) * DIM_ + (lane << 2));

  float dp = vi.x * vj.x + vi.y * vj.y + vi.z * vj.z + vi.w * vj.w;
#pragma unroll
  for (int off = 1; off < 64; off <<= 1) dp += __shfl_xor(dp, off, 64);
  const float invT = 1.0f / TEMP_;
  const float posT = dp * invT;

  float mi = -INFINITY, si = 0.f, mj = -INFINITY, sj = 0.f;
#pragma unroll
  for (int kk = 0; kk < K_ / 4; ++kk) {
    const int k = wave * (K_ / 4) + kk;
    const int idx = negidx[p * K_ + k];
    const float4 vn = *reinterpret_cast<const float4*>(nS + idx * DIM_ + (lane << 2));
    float di = vi.x * vn.x + vi.y * vn.y + vi.z * vn.z + vi.w * vn.w;
    float dj = vj.x * vn.x + vj.y * vn.y + vj.z * vn.z + vj.w * vn.w;
#pragma unroll
    for (int off = 1; off < 64; off <<= 1) {
      di += __shfl_xor(di, off, 64);
      dj += __shfl_xor(dj, off, 64);
    }
    const float li = di * invT;
    const float lj = dj * invT;
    if (li > mi) { si = si * expf(mi - li) + 1.f; mi = li; } else { si += expf(li - mi); }
    if (lj > mj) { sj = sj * expf(mj - lj) + 1.f; mj = lj; } else { sj += expf(lj - mj); }
  }

  __shared__ float pm[2][4], ps[2][4];
  if (lane == 0) {
    pm[0][wave] = mi; ps[0][wave] = si;
    pm[1][wave] = mj; ps[1][wave] = sj;
  }
  __syncthreads();
  if (tid == 0) {
    float total = 0.f;
#pragma unroll
    for (int side = 0; side < 2; ++side) {
      float m = posT;
      for (int w = 0; w < 4; ++w) m = fmaxf(m, pm[side][w]);
      float s = expf(posT - m);
      for (int w = 0; w < 4; ++w) s += ps[side][w] * expf(pm[side][w] - m);
      total += m + logf(s) - posT;  // lse - posT
    }
    atomicAdd(out, total / (2.0f * P_));
  }
}

extern "C" void kernel_launch(void* const* d_in, const int* in_sizes, int n_in,
                              void* d_out, int out_size, void* d_ws, size_t ws_size,
                              hipStream_t stream) {
  const float* emb = (const float*)d_in[0];
  const int* negidx = (const int*)d_in[1];
  float* out = (float*)d_out;

  // Workspace layout (floats):
  float* normsq = (float*)d_ws;                     // D*N = 524288
  float* psum = normsq + (size_t)D_ * N_;           // D*CHUNKS*DIM = 524288
  float* nS = psum + (size_t)D_ * CHUNKS * DIM_;    // 2*D*DIM = 32768

  k1_sums_norms<<<D_ * CHUNKS, 256, 0, stream>>>(emb, normsq, psum);
  k23_topk_samples<<<D_, 256, 0, stream>>>(emb, normsq, psum, nS, out);
  k4_loss<<<P_, 256, 0, stream>>>(nS, negidx, out);
}

// Round 11
// 143.315 us; speedup vs baseline: 1.9073x; 1.0410x over previous
//
#include <hip/hip_runtime.h>
#include <math.h>

// Problem constants (match reference)
constexpr int D_ = 64;
constexpr int N_ = 8192;
constexpr int DIM_ = 256;
constexpr int K_ = 32;
constexpr int L_ = 1;
constexpr int P_ = D_ - L_;  // 63
constexpr float TEMP_ = 0.1f;
constexpr float EPS_ = 1e-8f;

constexpr int CHUNKS = 32;   // blocks per d
constexpr int CROWS = 256;   // rows per block
constexpr int BATCH = 16;    // rows per wave per LDS round
constexpr int LDSTR = 65;    // scratch stride (words) -> 2-way (free) banks

// Kernel 1: r10 structure; ONLY change = wave-interleaved row mapping.
// Wave w reads rows {batch*64 + 4r + w}: the block's 4 waves jointly advance
// ONE contiguous 64-row (64KB) front instead of 4 private 16KB fronts.
// Streams chip-wide: 8192 -> 2048. Tests the DRAM row-thrash theory for the
// ~4.4 TB/s read wall (fills = 1 front = 6.7 TB/s).
__global__ __launch_bounds__(256, 4) void k1_sums_norms(const float* __restrict__ emb,
                                                        float* __restrict__ normsq,
                                                        float* __restrict__ psum) {
  const int b = blockIdx.x;
  const int d = b >> 5;
  const int chunk = b & 31;
  const int tid = threadIdx.x;
  const int wave = tid >> 6;
  const int lane = tid & 63;
  const float* base = emb + (size_t)d * N_ * DIM_;

  __shared__ __align__(16) float sq[4][BATCH * LDSTR];  // 16.25 KB

  float a0 = 0.f, a1 = 0.f, a2 = 0.f, a3 = 0.f;

  for (int batch = 0; batch < 4; ++batch) {
    const int brow0 = chunk * CROWS + batch * 64;  // block-front start row
#pragma unroll
    for (int r = 0; r < BATCH; ++r) {
      const int grow = brow0 + (r << 2) + wave;  // wave-interleaved
      const float4 v = *reinterpret_cast<const float4*>(base + (size_t)grow * DIM_ + (lane << 2));
      a0 += v.x; a1 += v.y; a2 += v.z; a3 += v.w;
      sq[wave][r * LDSTR + lane] = v.x * v.x + v.y * v.y + v.z * v.z + v.w * v.w;
    }
    // Own-wave transpose-reduce: 4 threads/row, 16 adds each, 2 shfl.
    {
      const int rr = tid >> 2;   // in [16*wave, 16*wave+16)
      const int q = tid & 3;
      const int r = rr & 15;
      const float* p = &sq[wave][r * LDSTR + q * 16];
      float s = 0.f;
#pragma unroll
      for (int i = 0; i < 16; ++i) s += p[i];
      s += __shfl_xor(s, 1, 64);
      s += __shfl_xor(s, 2, 64);
      if (q == 0) {
        const int row = brow0 + (r << 2) + wave;  // matches load mapping
        normsq[(size_t)d * N_ + row] = s;
      }
    }
  }

  // Colsum epilogue: own-wave stash, barrier, cross-wave combine, plain store.
  reinterpret_cast<float4*>(&sq[wave][0])[lane] = make_float4(a0, a1, a2, a3);
  __syncthreads();
  const float s = sq[0][tid] + sq[1][tid] + sq[2][tid] + sq[3][tid];
  psum[(size_t)(d * CHUNKS + chunk) * DIM_ + tid] = s;
}

// Kernel 2+3 fused (r10-exact): one block per d. Top-K by norm^2 (stable
// lowest-index tie-break, matching jnp.argsort(-norms)), then gather +
// samples + normalize.
__global__ __launch_bounds__(256) void k23_topk_samples(const float* __restrict__ emb,
                                                        const float* __restrict__ normsq,
                                                        const float* __restrict__ psum,
                                                        float* __restrict__ nS,
                                                        float* __restrict__ out) {
  const int d = blockIdx.x;
  const int tid = threadIdx.x;
  const int lane = tid & 63;
  const int wave = tid >> 6;

  __shared__ float vals[N_];  // 32 KB
  __shared__ unsigned long long wbest[4];
  __shared__ int topidx[K_];

  for (int i = tid; i < N_; i += 256) vals[i] = normsq[(size_t)d * N_ + i];

  // Per-dim colsum from the 32 per-chunk partials (independent of top-K).
  float s1 = 0.f;
#pragma unroll 8
  for (int c = 0; c < CHUNKS; ++c)
    s1 += psum[(size_t)(d * CHUNKS + c) * DIM_ + tid];

  __syncthreads();

  // key = (float bits)<<32 | (N-1-i): larger norm wins, then lower index
  // (valid: norms^2 >= 0 so the float bit pattern is order-preserving).
  unsigned long long my = 0ull;
#pragma unroll 8
  for (int r = 0; r < 32; ++r) {
    const int i = tid + (r << 8);
    const unsigned long long key =
        ((unsigned long long)__float_as_uint(vals[i]) << 32) | (unsigned)(N_ - 1 - i);
    if (key > my) my = key;
  }

  for (int k = 0; k < K_; ++k) {
    unsigned long long bw = my;
#pragma unroll
    for (int off = 1; off < 64; off <<= 1) {
      const unsigned long long o = __shfl_xor(bw, off, 64);
      if (o > bw) bw = o;
    }
    if (lane == 0) wbest[wave] = bw;
    __syncthreads();
    unsigned long long bb = wbest[0];
    for (int w = 1; w < 4; ++w)
      if (wbest[w] > bb) bb = wbest[w];
    const int idx = N_ - 1 - (int)(bb & 0xFFFFFFFFu);
    if (tid == 0) topidx[k] = idx;
    if ((idx & 255) == tid) {  // owner removes + rescans its strided chunk
      vals[idx] = 0.0f;
      my = 0ull;
      for (int r = 0; r < 32; ++r) {
        const int i = tid + (r << 8);
        const unsigned long long key =
            ((unsigned long long)__float_as_uint(vals[i]) << 32) | (unsigned)(N_ - 1 - i);
        if (key > my) my = key;
      }
    }
    __syncthreads();
  }

  // ---- samples + normalize ----
  const float* base = emb + (size_t)d * N_ * DIM_;
  float ts = 0.f;
#pragma unroll 4
  for (int k = 0; k < K_; ++k) {
    ts += base[(size_t)topidx[k] * DIM_ + tid];
  }
  const float s2 = s1 - ts;

  float q1 = s1 * s1, q2 = s2 * s2;
#pragma unroll
  for (int off = 32; off > 0; off >>= 1) {
    q1 += __shfl_down(q1, off, 64);
    q2 += __shfl_down(q2, off, 64);
  }
  __shared__ float w1[4], w2[4];
  __shared__ float inv1s, inv2s;
  if (lane == 0) { w1[wave] = q1; w2[wave] = q2; }
  __syncthreads();
  if (tid == 0) {
    const float n1 = sqrtf(w1[0] + w1[1] + w1[2] + w1[3]);
    const float n2 = sqrtf(w2[0] + w2[1] + w2[2] + w2[3]);
    inv1s = 1.0f / fmaxf(n1, EPS_);
    inv2s = 1.0f / fmaxf(n2, EPS_);
    if (d == 0) out[0] = 0.0f;  // zero loss accumulator (ordered before k4)
  }
  __syncthreads();
  nS[d * DIM_ + tid] = s1 * inv1s;
  nS[(D_ + d) * DIM_ + tid] = s2 * inv2s;
}

// Loss kernel: 4 waves per pair; wave w handles 8 negatives for both sides
// with an online (max, sumexp) held uniformly in all lanes, combined via LDS.
__global__ __launch_bounds__(256) void k4_loss(const float* __restrict__ nS,
                                               const int* __restrict__ negidx,
                                               float* __restrict__ out) {
  const int p = blockIdx.x;
  const int tid = threadIdx.x;
  const int wave = tid >> 6;
  const int lane = tid & 63;

  const float4 vi = *reinterpret_cast<const float4*>(nS + p * DIM_ + (lane << 2));
  const float4 vj = *reinterpret_cast<const float4*>(nS + (p + L_) * DIM_ + (lane << 2));

  float dp = vi.x * vj.x + vi.y * vj.y + vi.z * vj.z + vi.w * vj.w;
#pragma unroll
  for (int off = 1; off < 64; off <<= 1) dp += __shfl_xor(dp, off, 64);
  const float invT = 1.0f / TEMP_;
  const float posT = dp * invT;

  float mi = -INFINITY, si = 0.f, mj = -INFINITY, sj = 0.f;
#pragma unroll
  for (int kk = 0; kk < K_ / 4; ++kk) {
    const int k = wave * (K_ / 4) + kk;
    const int idx = negidx[p * K_ + k];
    const float4 vn = *reinterpret_cast<const float4*>(nS + idx * DIM_ + (lane << 2));
    float di = vi.x * vn.x + vi.y * vn.y + vi.z * vn.z + vi.w * vn.w;
    float dj = vj.x * vn.x + vj.y * vn.y + vj.z * vn.z + vj.w * vn.w;
#pragma unroll
    for (int off = 1; off < 64; off <<= 1) {
      di += __shfl_xor(di, off, 64);
      dj += __shfl_xor(dj, off, 64);
    }
    const float li = di * invT;
    const float lj = dj * invT;
    if (li > mi) { si = si * expf(mi - li) + 1.f; mi = li; } else { si += expf(li - mi); }
    if (lj > mj) { sj = sj * expf(mj - lj) + 1.f; mj = lj; } else { sj += expf(lj - mj); }
  }

  __shared__ float pm[2][4], ps[2][4];
  if (lane == 0) {
    pm[0][wave] = mi; ps[0][wave] = si;
    pm[1][wave] = mj; ps[1][wave] = sj;
  }
  __syncthreads();
  if (tid == 0) {
    float total = 0.f;
#pragma unroll
    for (int side = 0; side < 2; ++side) {
      float m = posT;
      for (int w = 0; w < 4; ++w) m = fmaxf(m, pm[side][w]);
      float s = expf(posT - m);
      for (int w = 0; w < 4; ++w) s += ps[side][w] * expf(pm[side][w] - m);
      total += m + logf(s) - posT;  // lse - posT
    }
    atomicAdd(out, total / (2.0f * P_));
  }
}

extern "C" void kernel_launch(void* const* d_in, const int* in_sizes, int n_in,
                              void* d_out, int out_size, void* d_ws, size_t ws_size,
                              hipStream_t stream) {
  const float* emb = (const float*)d_in[0];
  const int* negidx = (const int*)d_in[1];
  float* out = (float*)d_out;

  // Workspace layout (floats):
  float* normsq = (float*)d_ws;                     // D*N = 524288
  float* psum = normsq + (size_t)D_ * N_;           // D*CHUNKS*DIM = 524288
  float* nS = psum + (size_t)D_ * CHUNKS * DIM_;    // 2*D*DIM = 32768

  k1_sums_norms<<<D_ * CHUNKS, 256, 0, stream>>>(emb, normsq, psum);
  k23_topk_samples<<<D_, 256, 0, stream>>>(emb, normsq, psum, nS, out);
  k4_loss<<<P_, 256, 0, stream>>>(nS, negidx, out);
}

// Round 12
// 127.515 us; speedup vs baseline: 2.1436x; 1.1239x over previous
//
#include <hip/hip_runtime.h>
#include <math.h>

// Problem constants (match reference)
constexpr int D_ = 64;
constexpr int N_ = 8192;
constexpr int DIM_ = 256;
constexpr int K_ = 32;
constexpr int L_ = 1;
constexpr int P_ = D_ - L_;  // 63
constexpr float TEMP_ = 0.1f;
constexpr float EPS_ = 1e-8f;

constexpr int CHUNKS = 32;   // blocks per d
constexpr int CROWS = 256;   // rows per block
constexpr int BATCH = 16;    // rows per wave per LDS round
constexpr int LDSTR = 65;    // scratch stride (words) -> 2-way (free) banks

typedef float f32x4 __attribute__((ext_vector_type(4)));  // native vec for nontemporal

// Kernel 1: r11 structure (wave-interleaved single block front, 143.3us
// champion). ONLY change: hot-loop loads are nontemporal (nt flag -> no L2
// allocation). Tests the L2-allocation-cap theory for the ~4.6 TB/s read wall:
// zero-reuse streams that allocate L2 lines throttle on L2 fill occupancy;
// nt reads should stream past L2 toward the ~6.3-6.7 TB/s the fills prove.
__global__ __launch_bounds__(256, 4) void k1_sums_norms(const float* __restrict__ emb,
                                                        float* __restrict__ normsq,
                                                        float* __restrict__ psum) {
  const int b = blockIdx.x;
  const int d = b >> 5;
  const int chunk = b & 31;
  const int tid = threadIdx.x;
  const int wave = tid >> 6;
  const int lane = tid & 63;
  const float* base = emb + (size_t)d * N_ * DIM_;

  __shared__ __align__(16) float sq[4][BATCH * LDSTR];  // 16.25 KB

  float a0 = 0.f, a1 = 0.f, a2 = 0.f, a3 = 0.f;

  for (int batch = 0; batch < 4; ++batch) {
    const int brow0 = chunk * CROWS + batch * 64;  // block-front start row
#pragma unroll
    for (int r = 0; r < BATCH; ++r) {
      const int grow = brow0 + (r << 2) + wave;  // wave-interleaved
      const f32x4 v = __builtin_nontemporal_load(
          reinterpret_cast<const f32x4*>(base + (size_t)grow * DIM_ + (lane << 2)));
      a0 += v.x; a1 += v.y; a2 += v.z; a3 += v.w;
      sq[wave][r * LDSTR + lane] = v.x * v.x + v.y * v.y + v.z * v.z + v.w * v.w;
    }
    // Own-wave transpose-reduce: 4 threads/row, 16 adds each, 2 shfl.
    {
      const int rr = tid >> 2;   // in [16*wave, 16*wave+16)
      const int q = tid & 3;
      const int r = rr & 15;
      const float* p = &sq[wave][r * LDSTR + q * 16];
      float s = 0.f;
#pragma unroll
      for (int i = 0; i < 16; ++i) s += p[i];
      s += __shfl_xor(s, 1, 64);
      s += __shfl_xor(s, 2, 64);
      if (q == 0) {
        const int row = brow0 + (r << 2) + wave;  // matches load mapping
        normsq[(size_t)d * N_ + row] = s;
      }
    }
  }

  // Colsum epilogue: own-wave stash, barrier, cross-wave combine, plain store.
  reinterpret_cast<float4*>(&sq[wave][0])[lane] = make_float4(a0, a1, a2, a3);
  __syncthreads();
  const float s = sq[0][tid] + sq[1][tid] + sq[2][tid] + sq[3][tid];
  psum[(size_t)(d * CHUNKS + chunk) * DIM_ + tid] = s;
}

// Kernel 2+3 fused (r10-exact): one block per d. Top-K by norm^2 (stable
// lowest-index tie-break, matching jnp.argsort(-norms)), then gather +
// samples + normalize.
__global__ __launch_bounds__(256) void k23_topk_samples(const float* __restrict__ emb,
                                                        const float* __restrict__ normsq,
                                                        const float* __restrict__ psum,
                                                        float* __restrict__ nS,
                                                        float* __restrict__ out) {
  const int d = blockIdx.x;
  const int tid = threadIdx.x;
  const int lane = tid & 63;
  const int wave = tid >> 6;

  __shared__ float vals[N_];  // 32 KB
  __shared__ unsigned long long wbest[4];
  __shared__ int topidx[K_];

  for (int i = tid; i < N_; i += 256) vals[i] = normsq[(size_t)d * N_ + i];

  // Per-dim colsum from the 32 per-chunk partials (independent of top-K).
  float s1 = 0.f;
#pragma unroll 8
  for (int c = 0; c < CHUNKS; ++c)
    s1 += psum[(size_t)(d * CHUNKS + c) * DIM_ + tid];

  __syncthreads();

  // key = (float bits)<<32 | (N-1-i): larger norm wins, then lower index
  // (valid: norms^2 >= 0 so the float bit pattern is order-preserving).
  unsigned long long my = 0ull;
#pragma unroll 8
  for (int r = 0; r < 32; ++r) {
    const int i = tid + (r << 8);
    const unsigned long long key =
        ((unsigned long long)__float_as_uint(vals[i]) << 32) | (unsigned)(N_ - 1 - i);
    if (key > my) my = key;
  }

  for (int k = 0; k < K_; ++k) {
    unsigned long long bw = my;
#pragma unroll
    for (int off = 1; off < 64; off <<= 1) {
      const unsigned long long o = __shfl_xor(bw, off, 64);
      if (o > bw) bw = o;
    }
    if (lane == 0) wbest[wave] = bw;
    __syncthreads();
    unsigned long long bb = wbest[0];
    for (int w = 1; w < 4; ++w)
      if (wbest[w] > bb) bb = wbest[w];
    const int idx = N_ - 1 - (int)(bb & 0xFFFFFFFFu);
    if (tid == 0) topidx[k] = idx;
    if ((idx & 255) == tid) {  // owner removes + rescans its strided chunk
      vals[idx] = 0.0f;
      my = 0ull;
      for (int r = 0; r < 32; ++r) {
        const int i = tid + (r << 8);
        const unsigned long long key =
            ((unsigned long long)__float_as_uint(vals[i]) << 32) | (unsigned)(N_ - 1 - i);
        if (key > my) my = key;
      }
    }
    __syncthreads();
  }

  // ---- samples + normalize ----
  const float* base = emb + (size_t)d * N_ * DIM_;
  float ts = 0.f;
#pragma unroll 4
  for (int k = 0; k < K_; ++k) {
    ts += base[(size_t)topidx[k] * DIM_ + tid];
  }
  const float s2 = s1 - ts;

  float q1 = s1 * s1, q2 = s2 * s2;
#pragma unroll
  for (int off = 32; off > 0; off >>= 1) {
    q1 += __shfl_down(q1, off, 64);
    q2 += __shfl_down(q2, off, 64);
  }
  __shared__ float w1[4], w2[4];
  __shared__ float inv1s, inv2s;
  if (lane == 0) { w1[wave] = q1; w2[wave] = q2; }
  __syncthreads();
  if (tid == 0) {
    const float n1 = sqrtf(w1[0] + w1[1] + w1[2] + w1[3]);
    const float n2 = sqrtf(w2[0] + w2[1] + w2[2] + w2[3]);
    inv1s = 1.0f / fmaxf(n1, EPS_);
    inv2s = 1.0f / fmaxf(n2, EPS_);
    if (d == 0) out[0] = 0.0f;  // zero loss accumulator (ordered before k4)
  }
  __syncthreads();
  nS[d * DIM_ + tid] = s1 * inv1s;
  nS[(D_ + d) * DIM_ + tid] = s2 * inv2s;
}

// Loss kernel: 4 waves per pair; wave w handles 8 negatives for both sides
// with an online (max, sumexp) held uniformly in all lanes, combined via LDS.
__global__ __launch_bounds__(256) void k4_loss(const float* __restrict__ nS,
                                               const int* __restrict__ negidx,
                                               float* __restrict__ out) {
  const int p = blockIdx.x;
  const int tid = threadIdx.x;
  const int wave = tid >> 6;
  const int lane = tid & 63;

  const float4 vi = *reinterpret_cast<const float4*>(nS + p * DIM_ + (lane << 2));
  const float4 vj = *reinterpret_cast<const float4*>(nS + (p + L_) * DIM_ + (lane << 2));

  float dp = vi.x * vj.x + vi.y * vj.y + vi.z * vj.z + vi.w * vj.w;
#pragma unroll
  for (int off = 1; off < 64; off <<= 1) dp += __shfl_xor(dp, off, 64);
  const float invT = 1.0f / TEMP_;
  const float posT = dp * invT;

  float mi = -INFINITY, si = 0.f, mj = -INFINITY, sj = 0.f;
#pragma unroll
  for (int kk = 0; kk < K_ / 4; ++kk) {
    const int k = wave * (K_ / 4) + kk;
    const int idx = negidx[p * K_ + k];
    const float4 vn = *reinterpret_cast<const float4*>(nS + idx * DIM_ + (lane << 2));
    float di = vi.x * vn.x + vi.y * vn.y + vi.z * vn.z + vi.w * vn.w;
    float dj = vj.x * vn.x + vj.y * vn.y + vj.z * vn.z + vj.w * vn.w;
#pragma unroll
    for (int off = 1; off < 64; off <<= 1) {
      di += __shfl_xor(di, off, 64);
      dj += __shfl_xor(dj, off, 64);
    }
    const float li = di * invT;
    const float lj = dj * invT;
    if (li > mi) { si = si * expf(mi - li) + 1.f; mi = li; } else { si += expf(li - mi); }
    if (lj > mj) { sj = sj * expf(mj - lj) + 1.f; mj = lj; } else { sj += expf(lj - mj); }
  }

  __shared__ float pm[2][4], ps[2][4];
  if (lane == 0) {
    pm[0][wave] = mi; ps[0][wave] = si;
    pm[1][wave] = mj; ps[1][wave] = sj;
  }
  __syncthreads();
  if (tid == 0) {
    float total = 0.f;
#pragma unroll
    for (int side = 0; side < 2; ++side) {
      float m = posT;
      for (int w = 0; w < 4; ++w) m = fmaxf(m, pm[side][w]);
      float s = expf(posT - m);
      for (int w = 0; w < 4; ++w) s += ps[side][w] * expf(pm[side][w] - m);
      total += m + logf(s) - posT;  // lse - posT
    }
    atomicAdd(out, total / (2.0f * P_));
  }
}

extern "C" void kernel_launch(void* const* d_in, const int* in_sizes, int n_in,
                              void* d_out, int out_size, void* d_ws, size_t ws_size,
                              hipStream_t stream) {
  const float* emb = (const float*)d_in[0];
  const int* negidx = (const int*)d_in[1];
  float* out = (float*)d_out;

  // Workspace layout (floats):
  float* normsq = (float*)d_ws;                     // D*N = 524288
  float* psum = normsq + (size_t)D_ * N_;           // D*CHUNKS*DIM = 524288
  float* nS = psum + (size_t)D_ * CHUNKS * DIM_;    // 2*D*DIM = 32768

  k1_sums_norms<<<D_ * CHUNKS, 256, 0, stream>>>(emb, normsq, psum);
  k23_topk_samples<<<D_, 256, 0, stream>>>(emb, normsq, psum, nS, out);
  k4_loss<<<P_, 256, 0, stream>>>(nS, negidx, out);
}

// Round 13
// 111.090 us; speedup vs baseline: 2.4606x; 1.1479x over previous
//
#include <hip/hip_runtime.h>
#include <math.h>

// Problem constants (match reference)
constexpr int D_ = 64;
constexpr int N_ = 8192;
constexpr int DIM_ = 256;
constexpr int K_ = 32;
constexpr int L_ = 1;
constexpr int P_ = D_ - L_;  // 63
constexpr float TEMP_ = 0.1f;
constexpr float EPS_ = 1e-8f;

constexpr int CHUNKS = 32;   // blocks per d
constexpr int CROWS = 256;   // rows per block
constexpr int BATCH = 16;    // rows per wave per LDS round
constexpr int LDSTR = 65;    // scratch stride (words) -> 2-way (free) banks
constexpr int CAP = 256;     // threshold-select candidate capacity

typedef unsigned long long u64;
typedef float f32x4 __attribute__((ext_vector_type(4)));  // native vec for nontemporal

// Kernel 1 (r12 exact, 127.5us champion): wave-interleaved single block
// front + nontemporal loads (no L2 allocation). Validated theory: streaming
// reads throttle on L2 fill occupancy; nt bypass gave 4.6 -> 5.2 TB/s.
__global__ __launch_bounds__(256, 4) void k1_sums_norms(const float* __restrict__ emb,
                                                        float* __restrict__ normsq,
                                                        float* __restrict__ psum) {
  const int b = blockIdx.x;
  const int d = b >> 5;
  const int chunk = b & 31;
  const int tid = threadIdx.x;
  const int wave = tid >> 6;
  const int lane = tid & 63;
  const float* base = emb + (size_t)d * N_ * DIM_;

  __shared__ __align__(16) float sq[4][BATCH * LDSTR];  // 16.25 KB

  float a0 = 0.f, a1 = 0.f, a2 = 0.f, a3 = 0.f;

  for (int batch = 0; batch < 4; ++batch) {
    const int brow0 = chunk * CROWS + batch * 64;  // block-front start row
#pragma unroll
    for (int r = 0; r < BATCH; ++r) {
      const int grow = brow0 + (r << 2) + wave;  // wave-interleaved
      const f32x4 v = __builtin_nontemporal_load(
          reinterpret_cast<const f32x4*>(base + (size_t)grow * DIM_ + (lane << 2)));
      a0 += v.x; a1 += v.y; a2 += v.z; a3 += v.w;
      sq[wave][r * LDSTR + lane] = v.x * v.x + v.y * v.y + v.z * v.z + v.w * v.w;
    }
    // Own-wave transpose-reduce: 4 threads/row, 16 adds each, 2 shfl.
    {
      const int rr = tid >> 2;   // in [16*wave, 16*wave+16)
      const int q = tid & 3;
      const int r = rr & 15;
      const float* p = &sq[wave][r * LDSTR + q * 16];
      float s = 0.f;
#pragma unroll
      for (int i = 0; i < 16; ++i) s += p[i];
      s += __shfl_xor(s, 1, 64);
      s += __shfl_xor(s, 2, 64);
      if (q == 0) {
        const int row = brow0 + (r << 2) + wave;  // matches load mapping
        normsq[(size_t)d * N_ + row] = s;
      }
    }
  }

  // Colsum epilogue: own-wave stash, barrier, cross-wave combine, plain store.
  reinterpret_cast<float4*>(&sq[wave][0])[lane] = make_float4(a0, a1, a2, a3);
  __syncthreads();
  const float s = sq[0][tid] + sq[1][tid] + sq[2][tid] + sq[3][tid];
  psum[(size_t)(d * CHUNKS + chunk) * DIM_ + tid] = s;
}

// Bitonic sort of 256 u64 keys in LDS, descending; 256 threads, 36 stages.
__device__ __forceinline__ void bitonic256_desc(u64* a, int tid) {
  for (int size = 2; size <= 256; size <<= 1) {
    for (int stride = size >> 1; stride > 0; stride >>= 1) {
      __syncthreads();
      const int partner = tid ^ stride;
      if (partner > tid) {
        const u64 x = a[tid], y = a[partner];
        const bool desc = ((tid & size) == 0);
        if (desc ? (x < y) : (x > y)) { a[tid] = y; a[partner] = x; }
      }
    }
  }
  __syncthreads();
}

// Kernel 2+3: one block per d. Top-K via threshold-select (two passes + two
// 256-key bitonic sorts) with exact fallback to the iterative path; then
// gather + samples + normalize. Selection invariant: T = 32nd largest of the
// 256 per-thread maxima => >=32 keys >= T => all true top-32 keys >= T.
// Keys unique (index embedded) -> deterministic, stable (argsort-matching).
__global__ __launch_bounds__(256) void k23_topk_samples(const float* __restrict__ emb,
                                                        const float* __restrict__ normsq,
                                                        const float* __restrict__ psum,
                                                        float* __restrict__ nS,
                                                        float* __restrict__ out) {
  const int d = blockIdx.x;
  const int tid = threadIdx.x;
  const int lane = tid & 63;
  const int wave = tid >> 6;

  __shared__ float vals[N_];     // 32 KB
  __shared__ u64 work[CAP];      // 2 KB (maxima, then candidates)
  __shared__ int cnt;
  __shared__ int topidx[K_];
  __shared__ u64 wbest[4];       // fallback path

  for (int i = tid; i < N_; i += 256) vals[i] = normsq[(size_t)d * N_ + i];

  // Per-dim colsum from the 32 per-chunk partials (independent of top-K).
  float s1 = 0.f;
#pragma unroll 8
  for (int c = 0; c < CHUNKS; ++c)
    s1 += psum[(size_t)(d * CHUNKS + c) * DIM_ + tid];

  __syncthreads();

  // key = (float bits)<<32 | (N-1-i): larger norm wins, then lower index
  // (valid: norms^2 >= 0 so the float bit pattern is order-preserving).
  auto keyat = [&](int i) -> u64 {
    return ((u64)__float_as_uint(vals[i]) << 32) | (unsigned)(N_ - 1 - i);
  };

  // Phase A: per-thread max over strided chunk, sort maxima, T = 32nd largest.
  u64 my = 0ull;
#pragma unroll 8
  for (int r = 0; r < 32; ++r) {
    const u64 key = keyat(tid + (r << 8));
    if (key > my) my = key;
  }
  work[tid] = my;
  __syncthreads();
  bitonic256_desc(work, tid);
  const u64 T = work[31];
  __syncthreads();  // done reading work as maxima

  // Phase B: compact all keys >= T, then sort candidates.
  if (tid == 0) cnt = 0;
  __syncthreads();
#pragma unroll 8
  for (int r = 0; r < 32; ++r) {
    const u64 key = keyat(tid + (r << 8));
    if (key >= T) {
      const int p = atomicAdd(&cnt, 1);
      if (p < CAP) work[p] = key;
    }
  }
  __syncthreads();
  const int c = cnt;
  if (c <= CAP) {
    if (tid >= c) work[tid] = 0ull;  // pad
    __syncthreads();
    bitonic256_desc(work, tid);
    if (tid < K_) topidx[tid] = N_ - 1 - (int)(work[tid] & 0xFFFFFFFFull);
    __syncthreads();
  } else {
    // Fallback (exact, r10 path): 32 iterative argmax rounds.
    __syncthreads();
    u64 m2 = 0ull;
    for (int r = 0; r < 32; ++r) {
      const u64 key = keyat(tid + (r << 8));
      if (key > m2) m2 = key;
    }
    for (int k = 0; k < K_; ++k) {
      u64 bw = m2;
#pragma unroll
      for (int off = 1; off < 64; off <<= 1) {
        const u64 o = __shfl_xor(bw, off, 64);
        if (o > bw) bw = o;
      }
      if (lane == 0) wbest[wave] = bw;
      __syncthreads();
      u64 bb = wbest[0];
      for (int w = 1; w < 4; ++w)
        if (wbest[w] > bb) bb = wbest[w];
      const int idx = N_ - 1 - (int)(bb & 0xFFFFFFFFull);
      if (tid == 0) topidx[k] = idx;
      if ((idx & 255) == tid) {
        vals[idx] = 0.0f;
        m2 = 0ull;
        for (int r = 0; r < 32; ++r) {
          const u64 key = keyat(tid + (r << 8));
          if (key > m2) m2 = key;
        }
      }
      __syncthreads();
    }
  }

  // ---- samples + normalize ----
  const float* base = emb + (size_t)d * N_ * DIM_;
  float ts = 0.f;
#pragma unroll 4
  for (int k = 0; k < K_; ++k) {
    ts += base[(size_t)topidx[k] * DIM_ + tid];
  }
  const float s2 = s1 - ts;

  float q1 = s1 * s1, q2 = s2 * s2;
#pragma unroll
  for (int off = 32; off > 0; off >>= 1) {
    q1 += __shfl_down(q1, off, 64);
    q2 += __shfl_down(q2, off, 64);
  }
  __shared__ float w1[4], w2[4];
  __shared__ float inv1s, inv2s;
  if (lane == 0) { w1[wave] = q1; w2[wave] = q2; }
  __syncthreads();
  if (tid == 0) {
    const float n1 = sqrtf(w1[0] + w1[1] + w1[2] + w1[3]);
    const float n2 = sqrtf(w2[0] + w2[1] + w2[2] + w2[3]);
    inv1s = 1.0f / fmaxf(n1, EPS_);
    inv2s = 1.0f / fmaxf(n2, EPS_);
    if (d == 0) out[0] = 0.0f;  // zero loss accumulator (ordered before k4)
  }
  __syncthreads();
  nS[d * DIM_ + tid] = s1 * inv1s;
  nS[(D_ + d) * DIM_ + tid] = s2 * inv2s;
}

// Loss kernel: 4 waves per pair; wave w handles 8 negatives for both sides
// with an online (max, sumexp) held uniformly in all lanes, combined via LDS.
__global__ __launch_bounds__(256) void k4_loss(const float* __restrict__ nS,
                                               const int* __restrict__ negidx,
                                               float* __restrict__ out) {
  const int p = blockIdx.x;
  const int tid = threadIdx.x;
  const int wave = tid >> 6;
  const int lane = tid & 63;

  const float4 vi = *reinterpret_cast<const float4*>(nS + p * DIM_ + (lane << 2));
  const float4 vj = *reinterpret_cast<const float4*>(nS + (p + L_) * DIM_ + (lane << 2));

  float dp = vi.x * vj.x + vi.y * vj.y + vi.z * vj.z + vi.w * vj.w;
#pragma unroll
  for (int off = 1; off < 64; off <<= 1) dp += __shfl_xor(dp, off, 64);
  const float invT = 1.0f / TEMP_;
  const float posT = dp * invT;

  float mi = -INFINITY, si = 0.f, mj = -INFINITY, sj = 0.f;
#pragma unroll
  for (int kk = 0; kk < K_ / 4; ++kk) {
    const int k = wave * (K_ / 4) + kk;
    const int idx = negidx[p * K_ + k];
    const float4 vn = *reinterpret_cast<const float4*>(nS + idx * DIM_ + (lane << 2));
    float di = vi.x * vn.x + vi.y * vn.y + vi.z * vn.z + vi.w * vn.w;
    float dj = vj.x * vn.x + vj.y * vn.y + vj.z * vn.z + vj.w * vn.w;
#pragma unroll
    for (int off = 1; off < 64; off <<= 1) {
      di += __shfl_xor(di, off, 64);
      dj += __shfl_xor(dj, off, 64);
    }
    const float li = di * invT;
    const float lj = dj * invT;
    if (li > mi) { si = si * expf(mi - li) + 1.f; mi = li; } else { si += expf(li - mi); }
    if (lj > mj) { sj = sj * expf(mj - lj) + 1.f; mj = lj; } else { sj += expf(lj - mj); }
  }

  __shared__ float pm[2][4], ps[2][4];
  if (lane == 0) {
    pm[0][wave] = mi; ps[0][wave] = si;
    pm[1][wave] = mj; ps[1][wave] = sj;
  }
  __syncthreads();
  if (tid == 0) {
    float total = 0.f;
#pragma unroll
    for (int side = 0; side < 2; ++side) {
      float m = posT;
      for (int w = 0; w < 4; ++w) m = fmaxf(m, pm[side][w]);
      float s = expf(posT - m);
      for (int w = 0; w < 4; ++w) s += ps[side][w] * expf(pm[side][w] - m);
      total += m + logf(s) - posT;  // lse - posT
    }
    atomicAdd(out, total / (2.0f * P_));
  }
}

extern "C" void kernel_launch(void* const* d_in, const int* in_sizes, int n_in,
                              void* d_out, int out_size, void* d_ws, size_t ws_size,
                              hipStream_t stream) {
  const float* emb = (const float*)d_in[0];
  const int* negidx = (const int*)d_in[1];
  float* out = (float*)d_out;

  // Workspace layout (floats):
  float* normsq = (float*)d_ws;                     // D*N = 524288
  float* psum = normsq + (size_t)D_ * N_;           // D*CHUNKS*DIM = 524288
  float* nS = psum + (size_t)D_ * CHUNKS * DIM_;    // 2*D*DIM = 32768

  k1_sums_norms<<<D_ * CHUNKS, 256, 0, stream>>>(emb, normsq, psum);
  k23_topk_samples<<<D_, 256, 0, stream>>>(emb, normsq, psum, nS, out);
  k4_loss<<<P_, 256, 0, stream>>>(nS, negidx, out);
}